// Round 3
// baseline (309.065 us; speedup 1.0000x reference)
//
#include <hip/hip_runtime.h>
#include <cstdint>

typedef unsigned short u16;

#define AVG_LOG_F 1.4862356961977451f
#define MAXD 64

// ---- workspace float-unit offsets (weights region) ----
#define OFF_W2   3072   // pre_w2  fp32 [4][16][16]
#define OFF_PW1  4096   // post_w1 fp32 [4][256][16]
#define OFF_PW2  20480  // post_w2 fp32 [4][16][16]
#define OFF_LW   21504  // lin_w   fp32 [64][64]
#define OFF_PB1  25600
#define OFF_PB2  25664
#define OFF_QB1  25728
#define OFF_QB2  25792
#define OFF_LB   25856
#define OFF_LG   25920
#define OFF_LBN  25984
#define OFF_EWT  26128  // eWtab  fp32 [5][64]  (pb1 + ET.W1e, node-invariant)
#define IB       26448  // int region start (4B units)

__device__ __forceinline__ float bf2f(u16 u) {
    return __uint_as_float(((unsigned)u) << 16);
}
__device__ __forceinline__ u16 f2bf(float f) {
    unsigned u = __float_as_uint(f);
    u += 0x7fffu + ((u >> 16) & 1u);
    return (u16)(u >> 16);
}
__device__ __forceinline__ float rdin(const void* p, long j, int mode) {
    if (mode == 0) return bf2f(((const u16*)p)[j]);
    return ((const float*)p)[j];
}
template <int MODE>
__device__ __forceinline__ void load16c(const void* p, long base, float* o) {
    if (MODE == 0) {
        const u16* q = (const u16*)p + base;
        uint4 a = *(const uint4*)q;
        uint4 b = *(const uint4*)(q + 8);
        o[0]  = __uint_as_float(a.x << 16); o[1]  = __uint_as_float(a.x & 0xffff0000u);
        o[2]  = __uint_as_float(a.y << 16); o[3]  = __uint_as_float(a.y & 0xffff0000u);
        o[4]  = __uint_as_float(a.z << 16); o[5]  = __uint_as_float(a.z & 0xffff0000u);
        o[6]  = __uint_as_float(a.w << 16); o[7]  = __uint_as_float(a.w & 0xffff0000u);
        o[8]  = __uint_as_float(b.x << 16); o[9]  = __uint_as_float(b.x & 0xffff0000u);
        o[10] = __uint_as_float(b.y << 16); o[11] = __uint_as_float(b.y & 0xffff0000u);
        o[12] = __uint_as_float(b.z << 16); o[13] = __uint_as_float(b.z & 0xffff0000u);
        o[14] = __uint_as_float(b.w << 16); o[15] = __uint_as_float(b.w & 0xffff0000u);
    } else {
        const float* q = (const float*)p + base;
        float4 a = *(const float4*)q;
        float4 b = *(const float4*)(q + 4);
        float4 c = *(const float4*)(q + 8);
        float4 d = *(const float4*)(q + 12);
        o[0]=a.x; o[1]=a.y; o[2]=a.z; o[3]=a.w;
        o[4]=b.x; o[5]=b.y; o[6]=b.z; o[7]=b.w;
        o[8]=c.x; o[9]=c.y; o[10]=c.z; o[11]=c.w;
        o[12]=d.x; o[13]=d.y; o[14]=d.z; o[15]=d.w;
    }
}

// per-node precompute: Y[n][l] = x[n].W1_xj column,  XW[n][l] = x[n].W1_xi column
template <int MODE>
__device__ __forceinline__ void y_loop(const void* ax, const void* pre_w1, float* wsY, float* wsXW,
                                       int Nn, int wave, int nwaves, int l) {
    const int t = l >> 4, g = l & 15;
    float wxi[16], wxj[16];
#pragma unroll
    for (int f = 0; f < 16; f++) {
        wxi[f] = rdin(pre_w1, t * 768 + f * 16 + g, MODE);
        wxj[f] = rdin(pre_w1, t * 768 + (16 + f) * 16 + g, MODE);
    }
    for (int n = wave; n < Nn; n += nwaves) {
        float xj[16];
        load16c<MODE>(ax, (long)n * 64 + t * 16, xj);
        float accY = 0.f, accX = 0.f;
#pragma unroll
        for (int f = 0; f < 16; f++) {
            accY = fmaf(xj[f], wxj[f], accY);
            accX = fmaf(xj[f], wxi[f], accX);
        }
        wsY[(long)n * 64 + l]  = accY;
        wsXW[(long)n * 64 + l] = accX;
    }
}

// ---------------- 1: fused prep: weights->fp32, ET/eWtab, Y/XW precompute, edge scatter ----
__global__ __launch_bounds__(256) void k_prep(
    const int* __restrict__ dstp, const int* __restrict__ srcp, const int* __restrict__ bondp,
    const void* bond_emb, const void* edge_w, const void* edge_b,
    const void* pre_w1, const void* pre_b1, const void* pre_w2, const void* pre_b2,
    const void* post_w1, const void* post_b1, const void* post_w2, const void* post_b2,
    const void* lin_w, const void* lin_b, const void* ln_g, const void* ln_b,
    const void* ax, float* wsf, float* wsY, float* wsXW,
    int* __restrict__ cnt, int* __restrict__ pk, int* modep,
    int Nn, int E, int NIB)
{
    int tid = threadIdx.x;
    if ((int)blockIdx.x >= NIB) {            // ---- scatter part ----
        int e = ((int)blockIdx.x - NIB) * 256 + tid;
        if (e < E) {
            int d = dstp[e];
            int pos = atomicAdd(&cnt[d], 1);
            if (pos < MAXD) pk[d * MAXD + pos] = (srcp[e] << 3) | (bondp[e] & 7);
        }
        return;
    }
    // ---- init part ----
    __shared__ int csh;
    __shared__ float ET[80];
    if (tid == 0) csh = 0;
    __syncthreads();
    {
        unsigned v = ((const unsigned*)ax)[tid];
        unsigned lo = v & 0xffffu;
        int ee = (int)((lo >> 7) & 0xff);
        int isbf = (lo == 0u) || (ee >= 110 && ee <= 140);
        atomicAdd(&csh, isbf);
    }
    __syncthreads();
    int mode = (csh >= 192) ? 0 : 1;

    int b = (int)blockIdx.x;
    int gt = b * 256 + tid;
    int gs = NIB * 256;
    if (b == 0 && tid == 0) modep[0] = mode;

    for (int j = gt; j < 1024; j += gs)  wsf[OFF_W2 + j]  = rdin(pre_w2, j, mode);
    for (int j = gt; j < 16384; j += gs) wsf[OFF_PW1 + j] = rdin(post_w1, j, mode);
    for (int j = gt; j < 1024; j += gs)  wsf[OFF_PW2 + j] = rdin(post_w2, j, mode);
    for (int j = gt; j < 4096; j += gs)  wsf[OFF_LW + j]  = rdin(lin_w, j, mode);
    for (int j = gt; j < 64; j += gs) {
        wsf[OFF_PB1 + j] = rdin(pre_b1, j, mode);
        wsf[OFF_PB2 + j] = rdin(pre_b2, j, mode);
        wsf[OFF_QB1 + j] = rdin(post_b1, j, mode);
        wsf[OFF_QB2 + j] = rdin(post_b2, j, mode);
        wsf[OFF_LB + j]  = rdin(lin_b, j, mode);
        wsf[OFF_LG + j]  = rdin(ln_g, j, mode);
        wsf[OFF_LBN + j] = rdin(ln_b, j, mode);
    }
    if (b == 0) {
        if (tid < 80) {
            int bb = tid >> 4, f = tid & 15;
            float acc = rdin(edge_b, f, mode);
            for (int k = 0; k < 64; k++)
                acc = fmaf(rdin(bond_emb, bb * 64 + k, mode), rdin(edge_w, k * 16 + f, mode), acc);
            ET[tid] = acc;
        }
        __syncthreads();
        for (int j = tid; j < 320; j += 256) {
            int bb = j >> 6, ll = j & 63, tt = ll >> 4, gg = ll & 15;
            float acc = rdin(pre_b1, tt * 16 + gg, mode);
#pragma unroll
            for (int f = 0; f < 16; f++)
                acc = fmaf(ET[bb * 16 + f], rdin(pre_w1, tt * 768 + (32 + f) * 16 + gg, mode), acc);
            wsf[OFF_EWT + j] = acc;
        }
    }
    int wave = gt >> 6;
    int nwaves = gs >> 6;
    int l = tid & 63;
    if (mode == 0) y_loop<0>(ax, pre_w1, wsY, wsXW, Nn, wave, nwaves, l);
    else           y_loop<1>(ax, pre_w1, wsY, wsXW, Nn, wave, nwaves, l);
}

// ---------------- 2a: degree histogram (65 bins), LDS-aggregated ----------------
__global__ __launch_bounds__(256) void k_hist(const int* __restrict__ cnt, int* __restrict__ hist, int Nn)
{
    __shared__ int lh[65];
    int tid = threadIdx.x;
    if (tid < 65) lh[tid] = 0;
    __syncthreads();
    int n = blockIdx.x * 256 + tid;
    if (n < Nn) {
        int d = cnt[n]; if (d > 64) d = 64;
        atomicAdd(&lh[d], 1);
    }
    __syncthreads();
    if (tid < 65 && lh[tid]) atomicAdd(&hist[tid], lh[tid]);
}

// ---------------- 2b: place nodes into degree-sorted permutation ----------------
__global__ __launch_bounds__(256) void k_place(const int* __restrict__ cnt, const int* __restrict__ hist,
                                               int* __restrict__ binfill, int* __restrict__ perm, int Nn)
{
    __shared__ int lh[65], lbase[65], hsh[65];
    int tid = threadIdx.x;
    if (tid < 65) { lh[tid] = 0; hsh[tid] = hist[tid]; }
    __syncthreads();
    int n = blockIdx.x * 256 + tid;
    int b = 0, lpos = 0;
    if (n < Nn) {
        b = cnt[n]; if (b > 64) b = 64;
        lpos = atomicAdd(&lh[b], 1);
    }
    __syncthreads();
    if (tid < 65) {
        int c = lh[tid];
        lbase[tid] = c ? atomicAdd(&binfill[tid], c) : 0;
    }
    __syncthreads();
    if (n < Nn) {
        int off = 0;
        for (int i = 0; i < b; i++) off += hsh[i];
        perm[off + lbase[b] + lpos] = n;
    }
}

// ---------------- 3: fused node kernel: 8 deg-sorted nodes/block, co-computed MLPs --------
// Post-MLP weights (PW1 64KB + LW 16KB) streamed ONCE PER 8 NODES (f-split across 8 waves,
// partials in LDS, degree-scalers folded at write). Deg-sorted perm -> no barrier imbalance.
__global__ __launch_bounds__(512, 4) void k_node(
    const void* __restrict__ ax, const float* __restrict__ Yp, const float* __restrict__ XWp,
    const int* __restrict__ pk, const int* __restrict__ cnt, const int* __restrict__ perm,
    const float* __restrict__ wsf, void* __restrict__ outp,
    const int* __restrict__ modep, int Nn)
{
    __shared__ float hb[8][16][64];      // messages -> stats[0..4], p1[5], p2[6]
    __shared__ float zws[8][5][64];
    __shared__ float qp[8][8][64];       // [wave][node][chan] partials (scalers folded)
    __shared__ float xrow[8][64];        // x_i rows (also residual source)
    __shared__ float scl1s[8], scl2s[8];
    const int w = threadIdx.x >> 6;
    const int l = threadIdx.x & 63;
    const int t = l >> 4;
    const int g = l & 15;
    const int slot = blockIdx.x * 8 + w;
    const int mode = modep[0];
    const bool active = (slot < Nn);
    const int nn = active ? perm[slot] : 0;

    const float* W2  = wsf + OFF_W2  + t * 256;
    const float* PW1 = wsf + OFF_PW1 + t * 4096;
    const float* PW2 = wsf + OFF_PW2 + t * 256;

    float w2c[16];
#pragma unroll
    for (int f = 0; f < 16; f++) w2c[f] = W2[f * 16 + g];
    float pb2g = wsf[OFF_PB2 + t * 16 + g];
    float qb1g = wsf[OFF_QB1 + t * 16 + g];
    float qb2g = wsf[OFF_QB2 + t * 16 + g];

    int deg = active ? cnt[nn] : 0;
    if (deg > MAXD) deg = MAXD;

    int   pkvAll = pk[nn * MAXD + l];
    float XWv    = XWp[(long)nn * 64 + l];
    zws[w][0][l] = XWv + wsf[OFF_EWT + 0 * 64 + l];
    zws[w][1][l] = XWv + wsf[OFF_EWT + 1 * 64 + l];
    zws[w][2][l] = XWv + wsf[OFF_EWT + 2 * 64 + l];
    zws[w][3][l] = XWv + wsf[OFF_EWT + 3 * 64 + l];
    zws[w][4][l] = XWv + wsf[OFF_EWT + 4 * 64 + l];
    xrow[w][l]   = rdin(ax, (long)nn * 64 + l, mode);

    float s = 0.f, s2 = 0.f, mn = 3.0e38f, mx = -3.0e38f;

    auto phaseA = [&](int srclane, int k) {
        int v = __builtin_amdgcn_readlane(pkvAll, srclane);
        float yv = Yp[((long)(v >> 3) << 6) + l];
        float zt = zws[w][v & 7][l];
        hb[w][k][l] = fmaxf(yv + zt, 0.f);
    };
    auto phaseB = [&](int k) {
        const float4* hp = (const float4*)&hb[w][k][t * 16];
        float4 h0 = hp[0], h1 = hp[1], h2 = hp[2], h3 = hp[3];
        float m = pb2g;
        m = fmaf(h0.x, w2c[0],  m); m = fmaf(h0.y, w2c[1],  m);
        m = fmaf(h0.z, w2c[2],  m); m = fmaf(h0.w, w2c[3],  m);
        m = fmaf(h1.x, w2c[4],  m); m = fmaf(h1.y, w2c[5],  m);
        m = fmaf(h1.z, w2c[6],  m); m = fmaf(h1.w, w2c[7],  m);
        m = fmaf(h2.x, w2c[8],  m); m = fmaf(h2.y, w2c[9],  m);
        m = fmaf(h2.z, w2c[10], m); m = fmaf(h2.w, w2c[11], m);
        m = fmaf(h3.x, w2c[12], m); m = fmaf(h3.y, w2c[13], m);
        m = fmaf(h3.z, w2c[14], m); m = fmaf(h3.w, w2c[15], m);
        s += m;
        s2 = fmaf(m, m, s2);
        mn = fminf(mn, m);
        mx = fmaxf(mx, m);
    };

#pragma unroll
    for (int kb = 0; kb < MAXD; kb += 16) {
        if (kb >= deg) break;
        int B = deg - kb; if (B > 16) B = 16;
        if (B == 16) {
#pragma unroll
            for (int k = 0; k < 16; k++) phaseA(kb + k, k);
#pragma unroll 4
            for (int k = 0; k < 16; k++) phaseB(k);
        } else {
#pragma unroll 4
            for (int k = 0; k < B; k++) phaseA(kb + k, k);
#pragma unroll 4
            for (int k = 0; k < B; k++) phaseB(k);
        }
    }

    if (deg == 0) { mn = 0.f; mx = 0.f; }
    float cf = (float)(deg > 0 ? deg : 1);
    float inv = 1.0f / cf;
    float mean = s * inv;
    float var = s2 * inv - mean * mean;
    float sd = sqrtf(fmaxf(var, 0.f) + 1e-5f);
    float ldv = logf(cf + 1.0f);
    float sc1 = ldv * (1.0f / AVG_LOG_F);
    float sc2 = AVG_LOG_F / ldv;

    hb[w][0][l] = s;
    hb[w][1][l] = mean;
    hb[w][2][l] = mn;
    hb[w][3][l] = mx;
    hb[w][4][l] = sd;
    if (l == 0) { scl1s[w] = sc1; scl2s[w] = sc2; }
    __syncthreads();

    // ---- co-computed post-MLP layer 1: wave w handles f in [2w, 2w+2) for ALL 8 nodes;
    //      the 3 degree-scaler variants folded at write using each node's scalers.
    {
        float q0[8], q1[8], q2[8];
#pragma unroll
        for (int nd = 0; nd < 8; nd++) { q0[nd] = 0.f; q1[nd] = 0.f; q2[nd] = 0.f; }
        const int f0 = 2 * w;
#pragma unroll
        for (int fi = 0; fi < 2; fi++) {
            float wv = PW1[(f0 + fi) * 16 + g];
#pragma unroll
            for (int nd = 0; nd < 8; nd++)
                q0[nd] = fmaf(xrow[nd][t * 16 + f0 + fi], wv, q0[nd]);
        }
#pragma unroll
        for (int a = 0; a < 5; a++) {
#pragma unroll
            for (int fi = 0; fi < 2; fi++) {
                const int r = (16 + a * 16 + f0 + fi) * 16 + g;
                float w0  = PW1[r];
                float w1  = PW1[r + 1280];     // +80 rows (sc1 block)
                float w2v = PW1[r + 2560];     // +160 rows (sc2 block)
#pragma unroll
                for (int nd = 0; nd < 8; nd++) {
                    float x = hb[nd][a][t * 16 + f0 + fi];
                    q0[nd] = fmaf(x, w0,  q0[nd]);
                    q1[nd] = fmaf(x, w1,  q1[nd]);
                    q2[nd] = fmaf(x, w2v, q2[nd]);
                }
            }
        }
#pragma unroll
        for (int nd = 0; nd < 8; nd++)
            qp[w][nd][l] = fmaf(scl2s[nd], q2[nd], fmaf(scl1s[nd], q1[nd], q0[nd]));
    }
    __syncthreads();

    // ---- own-node combine + layer 2 ----
    {
        float q = qb1g;
#pragma unroll
        for (int ww = 0; ww < 8; ww++) q += qp[ww][w][l];
        float p1 = fmaxf(q, 0.f);
        hb[w][5][l] = p1;
        float pw2c[16];
#pragma unroll
        for (int f = 0; f < 16; f++) pw2c[f] = PW2[f * 16 + g];
        float m2 = qb2g;
        const float4* pp = (const float4*)&hb[w][5][t * 16];
        float4 p0 = pp[0], r1 = pp[1], r2 = pp[2], r3 = pp[3];
        m2 = fmaf(p0.x, pw2c[0],  m2); m2 = fmaf(p0.y, pw2c[1],  m2);
        m2 = fmaf(p0.z, pw2c[2],  m2); m2 = fmaf(p0.w, pw2c[3],  m2);
        m2 = fmaf(r1.x, pw2c[4],  m2); m2 = fmaf(r1.y, pw2c[5],  m2);
        m2 = fmaf(r1.z, pw2c[6],  m2); m2 = fmaf(r1.w, pw2c[7],  m2);
        m2 = fmaf(r2.x, pw2c[8],  m2); m2 = fmaf(r2.y, pw2c[9],  m2);
        m2 = fmaf(r2.z, pw2c[10], m2); m2 = fmaf(r2.w, pw2c[11], m2);
        m2 = fmaf(r3.x, pw2c[12], m2); m2 = fmaf(r3.y, pw2c[13], m2);
        m2 = fmaf(r3.z, pw2c[14], m2); m2 = fmaf(r3.w, pw2c[15], m2);
        hb[w][6][l] = m2;
    }
    __syncthreads();

    // ---- co-computed final 64x64 linear: wave w handles f in [8w, 8w+8) for 8 nodes
    {
        const float* LW = wsf + OFF_LW;
        const int fb = w * 8;
        float lw[8];
#pragma unroll
        for (int nd = 0; nd < 8; nd++) lw[nd] = 0.f;
#pragma unroll
        for (int c = 0; c < 2; c++) {
            float pa[8][4];
#pragma unroll
            for (int nd = 0; nd < 8; nd++) {
                float4 v = *(const float4*)&hb[nd][6][fb + 4 * c];
                pa[nd][0] = v.x; pa[nd][1] = v.y; pa[nd][2] = v.z; pa[nd][3] = v.w;
            }
#pragma unroll
            for (int fi = 0; fi < 4; fi++) {
                float wl = LW[(fb + 4 * c + fi) * 64 + l];
#pragma unroll
                for (int nd = 0; nd < 8; nd++) lw[nd] = fmaf(pa[nd][fi], wl, lw[nd]);
            }
        }
#pragma unroll
        for (int nd = 0; nd < 8; nd++) qp[w][nd][l] = lw[nd];
    }
    __syncthreads();

    // ---- own-node LayerNorm + ReLU + residual ----
    {
        float a = wsf[OFF_LB + l];
#pragma unroll
        for (int ww = 0; ww < 8; ww++) a += qp[ww][w][l];
        float s1 = a, sq = a * a;
#pragma unroll
        for (int o = 1; o < 64; o <<= 1) { s1 += __shfl_xor(s1, o); sq += __shfl_xor(sq, o); }
        float mu = s1 * (1.0f / 64.0f);
        float varl = sq * (1.0f / 64.0f) - mu * mu;
        float ln = (a - mu) * rsqrtf(varl + 1e-5f) * wsf[OFF_LG + l] + wsf[OFF_LBN + l];
        if (active) {
            long idx = (long)nn * 64 + l;
            float res = xrow[w][l] + fmaxf(ln, 0.f);
            if (mode == 0) ((u16*)outp)[idx] = f2bf(res);
            else           ((float*)outp)[idx] = res;
        }
    }
}

extern "C" void kernel_launch(void* const* d_in, const int* in_sizes, int n_in,
                              void* d_out, int out_size, void* d_ws, size_t ws_size,
                              hipStream_t stream) {
    const void* atom_x   = d_in[0];
    const void* bond_emb = d_in[1];
    const void* edge_w   = d_in[2];
    const void* edge_b   = d_in[3];
    const void* pre_w1   = d_in[4];
    const void* pre_b1   = d_in[5];
    const void* pre_w2   = d_in[6];
    const void* pre_b2   = d_in[7];
    const void* post_w1  = d_in[8];
    const void* post_b1  = d_in[9];
    const void* post_w2  = d_in[10];
    const void* post_b2  = d_in[11];
    const void* lin_w    = d_in[12];
    const void* lin_b    = d_in[13];
    const void* ln_g     = d_in[14];
    const void* ln_b     = d_in[15];
    const int* bond_x    = (const int*)d_in[16];
    const int* aei       = (const int*)d_in[17];

    int E  = in_sizes[16];
    int Nn = in_sizes[0] / 64;
    const int* srcp = aei;
    const int* dstp = aei + E;

    float* wsf = (float*)d_ws;
    int*   wsi = (int*)d_ws;

    size_t o = IB;
    int* modep   = wsi + o; o += 16;
    int* cnt     = wsi + o; o += Nn;
    int* hist    = wsi + o; o += 65;
    int* binfill = wsi + o; o += 65;
    o = (o + 63) & ~(size_t)63;
    int* pk      = wsi + o; o += (size_t)Nn * MAXD;
    float* Yp    = (float*)(wsi + o); o += (size_t)Nn * 64;
    float* XWp   = (float*)(wsi + o); o += (size_t)Nn * 64;
    int* perm    = wsi + o; o += Nn;
    // ws usage ~39.4 MB

    const int NIB  = 1600;
    const int SBLK = (E + 255) / 256;
    const int NB   = (Nn + 255) / 256;

    (void)hipMemsetAsync(cnt, 0, (size_t)(Nn + 130) * sizeof(int), stream);
    k_prep<<<NIB + SBLK, 256, 0, stream>>>(dstp, srcp, bond_x,
                                           bond_emb, edge_w, edge_b,
                                           pre_w1, pre_b1, pre_w2, pre_b2,
                                           post_w1, post_b1, post_w2, post_b2,
                                           lin_w, lin_b, ln_g, ln_b,
                                           atom_x, wsf, Yp, XWp, cnt, pk, modep, Nn, E, NIB);
    k_hist<<<NB, 256, 0, stream>>>(cnt, hist, Nn);
    k_place<<<NB, 256, 0, stream>>>(cnt, hist, binfill, perm, Nn);
    dim3 gn((Nn + 7) / 8, 1, 1);
    k_node<<<gn, 512, 0, stream>>>(atom_x, Yp, XWp, pk, cnt, perm, wsf, d_out, modep, Nn);
}

// Round 4
// 308.034 us; speedup vs baseline: 1.0033x; 1.0033x over previous
//
#include <hip/hip_runtime.h>
#include <cstdint>

typedef unsigned short u16;

#define AVG_LOG_F 1.4862356961977451f
#define MAXD 64

// ---- workspace float-unit offsets (weights region) ----
#define OFF_W2   3072   // pre_w2  fp32 [4][16][16]
#define OFF_PW1  4096   // post_w1 fp32 [4][256][16]
#define OFF_PW2  20480  // post_w2 fp32 [4][16][16]
#define OFF_LW   21504  // lin_w   fp32 [64][64]
#define OFF_PB1  25600
#define OFF_PB2  25664
#define OFF_QB1  25728
#define OFF_QB2  25792
#define OFF_LB   25856
#define OFF_LG   25920
#define OFF_LBN  25984
#define OFF_EWT  26128  // eWtab  fp32 [5][64]  (pb1 + ET.W1e, node-invariant)
#define IB       26448  // int region start (4B units)

__device__ __forceinline__ float bf2f(u16 u) {
    return __uint_as_float(((unsigned)u) << 16);
}
__device__ __forceinline__ u16 f2bf(float f) {
    unsigned u = __float_as_uint(f);
    u += 0x7fffu + ((u >> 16) & 1u);
    return (u16)(u >> 16);
}
__device__ __forceinline__ float rdin(const void* p, long j, int mode) {
    if (mode == 0) return bf2f(((const u16*)p)[j]);
    return ((const float*)p)[j];
}
template <int MODE>
__device__ __forceinline__ void load16c(const void* p, long base, float* o) {
    if (MODE == 0) {
        const u16* q = (const u16*)p + base;
        uint4 a = *(const uint4*)q;
        uint4 b = *(const uint4*)(q + 8);
        o[0]  = __uint_as_float(a.x << 16); o[1]  = __uint_as_float(a.x & 0xffff0000u);
        o[2]  = __uint_as_float(a.y << 16); o[3]  = __uint_as_float(a.y & 0xffff0000u);
        o[4]  = __uint_as_float(a.z << 16); o[5]  = __uint_as_float(a.z & 0xffff0000u);
        o[6]  = __uint_as_float(a.w << 16); o[7]  = __uint_as_float(a.w & 0xffff0000u);
        o[8]  = __uint_as_float(b.x << 16); o[9]  = __uint_as_float(b.x & 0xffff0000u);
        o[10] = __uint_as_float(b.y << 16); o[11] = __uint_as_float(b.y & 0xffff0000u);
        o[12] = __uint_as_float(b.z << 16); o[13] = __uint_as_float(b.z & 0xffff0000u);
        o[14] = __uint_as_float(b.w << 16); o[15] = __uint_as_float(b.w & 0xffff0000u);
    } else {
        const float* q = (const float*)p + base;
        float4 a = *(const float4*)q;
        float4 b = *(const float4*)(q + 4);
        float4 c = *(const float4*)(q + 8);
        float4 d = *(const float4*)(q + 12);
        o[0]=a.x; o[1]=a.y; o[2]=a.z; o[3]=a.w;
        o[4]=b.x; o[5]=b.y; o[6]=b.z; o[7]=b.w;
        o[8]=c.x; o[9]=c.y; o[10]=c.z; o[11]=c.w;
        o[12]=d.x; o[13]=d.y; o[14]=d.z; o[15]=d.w;
    }
}

// per-node precompute: Y[n][l] = x[n].W1_xj column,  XW[n][l] = x[n].W1_xi column
template <int MODE>
__device__ __forceinline__ void y_loop(const void* ax, const void* pre_w1, float* wsY, float* wsXW,
                                       int Nn, int wave, int nwaves, int l) {
    const int t = l >> 4, g = l & 15;
    float wxi[16], wxj[16];
#pragma unroll
    for (int f = 0; f < 16; f++) {
        wxi[f] = rdin(pre_w1, t * 768 + f * 16 + g, MODE);
        wxj[f] = rdin(pre_w1, t * 768 + (16 + f) * 16 + g, MODE);
    }
    for (int n = wave; n < Nn; n += nwaves) {
        float xj[16];
        load16c<MODE>(ax, (long)n * 64 + t * 16, xj);
        float accY = 0.f, accX = 0.f;
#pragma unroll
        for (int f = 0; f < 16; f++) {
            accY = fmaf(xj[f], wxj[f], accY);
            accX = fmaf(xj[f], wxi[f], accX);
        }
        wsY[(long)n * 64 + l]  = accY;
        wsXW[(long)n * 64 + l] = accX;
    }
}

// ---------------- 1: fused prep: weights->fp32, ET/eWtab, Y/XW precompute, edge scatter ----
__global__ __launch_bounds__(256) void k_prep(
    const int* __restrict__ dstp, const int* __restrict__ srcp, const int* __restrict__ bondp,
    const void* bond_emb, const void* edge_w, const void* edge_b,
    const void* pre_w1, const void* pre_b1, const void* pre_w2, const void* pre_b2,
    const void* post_w1, const void* post_b1, const void* post_w2, const void* post_b2,
    const void* lin_w, const void* lin_b, const void* ln_g, const void* ln_b,
    const void* ax, float* wsf, float* wsY, float* wsXW,
    int* __restrict__ cnt, int* __restrict__ pk, int* modep,
    int Nn, int E, int NIB)
{
    int tid = threadIdx.x;
    if ((int)blockIdx.x >= NIB) {            // ---- scatter part ----
        int e = ((int)blockIdx.x - NIB) * 256 + tid;
        if (e < E) {
            int d = dstp[e];
            int pos = atomicAdd(&cnt[d], 1);
            // pack (src*64)<<3 | bond  ->  k_node row offset = (v>>3)+l, bond = v&7
            if (pos < MAXD) pk[d * MAXD + pos] = (srcp[e] << 9) | (bondp[e] & 7);
        }
        return;
    }
    // ---- init part ----
    __shared__ int csh;
    __shared__ float ET[80];
    if (tid == 0) csh = 0;
    __syncthreads();
    {
        unsigned v = ((const unsigned*)ax)[tid];
        unsigned lo = v & 0xffffu;
        int ee = (int)((lo >> 7) & 0xff);
        int isbf = (lo == 0u) || (ee >= 110 && ee <= 140);
        atomicAdd(&csh, isbf);
    }
    __syncthreads();
    int mode = (csh >= 192) ? 0 : 1;

    int b = (int)blockIdx.x;
    int gt = b * 256 + tid;
    int gs = NIB * 256;
    if (b == 0 && tid == 0) modep[0] = mode;

    for (int j = gt; j < 1024; j += gs)  wsf[OFF_W2 + j]  = rdin(pre_w2, j, mode);
    for (int j = gt; j < 16384; j += gs) wsf[OFF_PW1 + j] = rdin(post_w1, j, mode);
    for (int j = gt; j < 1024; j += gs)  wsf[OFF_PW2 + j] = rdin(post_w2, j, mode);
    for (int j = gt; j < 4096; j += gs)  wsf[OFF_LW + j]  = rdin(lin_w, j, mode);
    for (int j = gt; j < 64; j += gs) {
        wsf[OFF_PB1 + j] = rdin(pre_b1, j, mode);
        wsf[OFF_PB2 + j] = rdin(pre_b2, j, mode);
        wsf[OFF_QB1 + j] = rdin(post_b1, j, mode);
        wsf[OFF_QB2 + j] = rdin(post_b2, j, mode);
        wsf[OFF_LB + j]  = rdin(lin_b, j, mode);
        wsf[OFF_LG + j]  = rdin(ln_g, j, mode);
        wsf[OFF_LBN + j] = rdin(ln_b, j, mode);
    }
    if (b == 0) {
        if (tid < 80) {
            int bb = tid >> 4, f = tid & 15;
            float acc = rdin(edge_b, f, mode);
            for (int k = 0; k < 64; k++)
                acc = fmaf(rdin(bond_emb, bb * 64 + k, mode), rdin(edge_w, k * 16 + f, mode), acc);
            ET[tid] = acc;
        }
        __syncthreads();
        for (int j = tid; j < 320; j += 256) {
            int bb = j >> 6, ll = j & 63, tt = ll >> 4, gg = ll & 15;
            float acc = rdin(pre_b1, tt * 16 + gg, mode);
#pragma unroll
            for (int f = 0; f < 16; f++)
                acc = fmaf(ET[bb * 16 + f], rdin(pre_w1, tt * 768 + (32 + f) * 16 + gg, mode), acc);
            wsf[OFF_EWT + j] = acc;
        }
    }
    int wave = gt >> 6;
    int nwaves = gs >> 6;
    int l = tid & 63;
    if (mode == 0) y_loop<0>(ax, pre_w1, wsY, wsXW, Nn, wave, nwaves, l);
    else           y_loop<1>(ax, pre_w1, wsY, wsXW, Nn, wave, nwaves, l);
}

// ---------------- 2: fused node kernel: aggregation per-wave, post-MLP co-computed ----------
// LDS trimmed to 26.6KB -> 6 blocks/CU (24 waves, 75% occ) for gather-latency hiding.
// Degree-scaler accumulators folded at qp-write (linear, scalers are per-node scalars).
__global__ __launch_bounds__(256, 6) void k_node(
    const void* __restrict__ ax, const float* __restrict__ Yp, const float* __restrict__ XWp,
    const int* __restrict__ pk, const int* __restrict__ cnt,
    const float* __restrict__ wsf, void* __restrict__ outp,
    const int* __restrict__ modep, int Nn)
{
    __shared__ float hb[4][16][64];      // message buffer -> stats[0..4], p1[5], p2[6]
    __shared__ float zws[4][5][64];
    __shared__ float qp[4][4][64];       // [wave][node][chan] partials (scalers folded)
    __shared__ float xrow[4][64];        // x_i rows (also residual source)
    __shared__ float scl1s[4], scl2s[4];
    const int w = threadIdx.x >> 6;
    const int l = threadIdx.x & 63;
    const int t = l >> 4;
    const int g = l & 15;
    const int n = blockIdx.x * 4 + w;
    const int mode = modep[0];
    const bool active = (n < Nn);
    const int nn = active ? n : 0;

    const float* W2  = wsf + OFF_W2  + t * 256;
    const float* PW1 = wsf + OFF_PW1 + t * 4096;
    const float* PW2 = wsf + OFF_PW2 + t * 256;

    float w2c[16];
#pragma unroll
    for (int f = 0; f < 16; f++) w2c[f] = W2[f * 16 + g];
    float pb2g = wsf[OFF_PB2 + t * 16 + g];
    float qb1g = wsf[OFF_QB1 + t * 16 + g];
    float qb2g = wsf[OFF_QB2 + t * 16 + g];

    int deg = active ? cnt[nn] : 0;
    if (deg > MAXD) deg = MAXD;

    int   pkvAll = pk[nn * MAXD + l];
    float XWv    = XWp[(long)nn * 64 + l];
    zws[w][0][l] = XWv + wsf[OFF_EWT + 0 * 64 + l];
    zws[w][1][l] = XWv + wsf[OFF_EWT + 1 * 64 + l];
    zws[w][2][l] = XWv + wsf[OFF_EWT + 2 * 64 + l];
    zws[w][3][l] = XWv + wsf[OFF_EWT + 3 * 64 + l];
    zws[w][4][l] = XWv + wsf[OFF_EWT + 4 * 64 + l];
    xrow[w][l]   = rdin(ax, (long)nn * 64 + l, mode);

    float s = 0.f, s2 = 0.f, mn = 3.0e38f, mx = -3.0e38f;

    auto phaseA = [&](int srclane, int k) {
        int v = __builtin_amdgcn_readlane(pkvAll, srclane);
        float yv = Yp[(v >> 3) + l];          // v>>3 = src*64 (packed in scatter)
        float zt = zws[w][v & 7][l];
        hb[w][k][l] = fmaxf(yv + zt, 0.f);
    };
    auto phaseB = [&](int k) {
        const float4* hp = (const float4*)&hb[w][k][t * 16];
        float4 h0 = hp[0], h1 = hp[1], h2 = hp[2], h3 = hp[3];
        float m = pb2g;
        m = fmaf(h0.x, w2c[0],  m); m = fmaf(h0.y, w2c[1],  m);
        m = fmaf(h0.z, w2c[2],  m); m = fmaf(h0.w, w2c[3],  m);
        m = fmaf(h1.x, w2c[4],  m); m = fmaf(h1.y, w2c[5],  m);
        m = fmaf(h1.z, w2c[6],  m); m = fmaf(h1.w, w2c[7],  m);
        m = fmaf(h2.x, w2c[8],  m); m = fmaf(h2.y, w2c[9],  m);
        m = fmaf(h2.z, w2c[10], m); m = fmaf(h2.w, w2c[11], m);
        m = fmaf(h3.x, w2c[12], m); m = fmaf(h3.y, w2c[13], m);
        m = fmaf(h3.z, w2c[14], m); m = fmaf(h3.w, w2c[15], m);
        s += m;
        s2 = fmaf(m, m, s2);
        mn = fminf(mn, m);
        mx = fmaxf(mx, m);
    };

#pragma unroll
    for (int kb = 0; kb < MAXD; kb += 16) {
        if (kb >= deg) break;
        int B = deg - kb; if (B > 16) B = 16;
        if (B == 16) {
#pragma unroll
            for (int k = 0; k < 16; k++) phaseA(kb + k, k);   // literal lanes -> v_readlane
#pragma unroll 4
            for (int k = 0; k < 16; k++) phaseB(k);
        } else {
            for (int k = 0; k < B; k++) phaseA(kb + k, k);
            for (int k = 0; k < B; k++) phaseB(k);
        }
    }

    if (deg == 0) { mn = 0.f; mx = 0.f; }
    float cf = (float)(deg > 0 ? deg : 1);
    float inv = 1.0f / cf;
    float mean = s * inv;
    float var = s2 * inv - mean * mean;
    float sd = sqrtf(fmaxf(var, 0.f) + 1e-5f);
    float ldv = logf(cf + 1.0f);
    float sc1 = ldv * (1.0f / AVG_LOG_F);
    float sc2 = AVG_LOG_F / ldv;

    hb[w][0][l] = s;
    hb[w][1][l] = mean;
    hb[w][2][l] = mn;
    hb[w][3][l] = mx;
    hb[w][4][l] = sd;
    if (l == 0) { scl1s[w] = sc1; scl2s[w] = sc2; }
    __syncthreads();

    // ---- co-computed post-MLP layer 1: this wave handles f in [4w, 4w+4) for ALL 4 nodes;
    //      3 degree-scaler variants folded at write using each node's scalers.
    const int F0 = w * 4;
    float q0[4] = {0,0,0,0}, q1[4] = {0,0,0,0}, q2[4] = {0,0,0,0};
    {
        float xa[4][4];
#pragma unroll
        for (int nd = 0; nd < 4; nd++) {
            float4 v = *(const float4*)&xrow[nd][t * 16 + F0];
            xa[nd][0] = v.x; xa[nd][1] = v.y; xa[nd][2] = v.z; xa[nd][3] = v.w;
        }
#pragma unroll
        for (int fi = 0; fi < 4; fi++) {
            float wv = PW1[(F0 + fi) * 16 + g];
#pragma unroll
            for (int nd = 0; nd < 4; nd++) q0[nd] = fmaf(xa[nd][fi], wv, q0[nd]);
        }
    }
#pragma unroll
    for (int a = 0; a < 5; a++) {
        float xa[4][4];
#pragma unroll
        for (int nd = 0; nd < 4; nd++) {
            float4 v = *(const float4*)&hb[nd][a][t * 16 + F0];
            xa[nd][0] = v.x; xa[nd][1] = v.y; xa[nd][2] = v.z; xa[nd][3] = v.w;
        }
        const int rb = 16 + a * 16;
#pragma unroll
        for (int fi = 0; fi < 4; fi++) {
            const int r = (rb + F0 + fi) * 16 + g;
            float w0  = PW1[r];
            float w1  = PW1[r + 80 * 16];
            float w2v = PW1[r + 160 * 16];
#pragma unroll
            for (int nd = 0; nd < 4; nd++) {
                float x = xa[nd][fi];
                q0[nd] = fmaf(x, w0,  q0[nd]);
                q1[nd] = fmaf(x, w1,  q1[nd]);
                q2[nd] = fmaf(x, w2v, q2[nd]);
            }
        }
    }
#pragma unroll
    for (int nd = 0; nd < 4; nd++)
        qp[w][nd][l] = fmaf(scl2s[nd], q2[nd], fmaf(scl1s[nd], q1[nd], q0[nd]));
    __syncthreads();

    // ---- own-node combine + layer 2 ----
    {
        float q0s = qp[0][w][l] + qp[1][w][l] + qp[2][w][l] + qp[3][w][l];
        float p1 = fmaxf(q0s + qb1g, 0.f);
        hb[w][5][l] = p1;
        float pw2c[16];
#pragma unroll
        for (int f = 0; f < 16; f++) pw2c[f] = PW2[f * 16 + g];
        float m2 = qb2g;
        const float4* pp = (const float4*)&hb[w][5][t * 16];
        float4 p0 = pp[0], r1 = pp[1], r2 = pp[2], r3 = pp[3];
        m2 = fmaf(p0.x, pw2c[0],  m2); m2 = fmaf(p0.y, pw2c[1],  m2);
        m2 = fmaf(p0.z, pw2c[2],  m2); m2 = fmaf(p0.w, pw2c[3],  m2);
        m2 = fmaf(r1.x, pw2c[4],  m2); m2 = fmaf(r1.y, pw2c[5],  m2);
        m2 = fmaf(r1.z, pw2c[6],  m2); m2 = fmaf(r1.w, pw2c[7],  m2);
        m2 = fmaf(r2.x, pw2c[8],  m2); m2 = fmaf(r2.y, pw2c[9],  m2);
        m2 = fmaf(r2.z, pw2c[10], m2); m2 = fmaf(r2.w, pw2c[11], m2);
        m2 = fmaf(r3.x, pw2c[12], m2); m2 = fmaf(r3.y, pw2c[13], m2);
        m2 = fmaf(r3.z, pw2c[14], m2); m2 = fmaf(r3.w, pw2c[15], m2);
        hb[w][6][l] = m2;
    }
    __syncthreads();

    // ---- co-computed final 64x64 linear: this wave handles f in [16w, 16w+16) for 4 nodes
    {
        const float* LW = wsf + OFF_LW;
        const int fb = w * 16;
        float lw[4] = {0,0,0,0};
#pragma unroll
        for (int c = 0; c < 4; c++) {
            float pa[4][4];
#pragma unroll
            for (int nd = 0; nd < 4; nd++) {
                float4 v = *(const float4*)&hb[nd][6][fb + 4 * c];
                pa[nd][0] = v.x; pa[nd][1] = v.y; pa[nd][2] = v.z; pa[nd][3] = v.w;
            }
#pragma unroll
            for (int fi = 0; fi < 4; fi++) {
                float wl = LW[(fb + 4 * c + fi) * 64 + l];
#pragma unroll
                for (int nd = 0; nd < 4; nd++) lw[nd] = fmaf(pa[nd][fi], wl, lw[nd]);
            }
        }
#pragma unroll
        for (int nd = 0; nd < 4; nd++) qp[w][nd][l] = lw[nd];
    }
    __syncthreads();

    // ---- own-node LayerNorm + ReLU + residual ----
    {
        float a = wsf[OFF_LB + l] + qp[0][w][l] + qp[1][w][l] + qp[2][w][l] + qp[3][w][l];
        float s1 = a, sq = a * a;
#pragma unroll
        for (int o = 1; o < 64; o <<= 1) { s1 += __shfl_xor(s1, o); sq += __shfl_xor(sq, o); }
        float mu = s1 * (1.0f / 64.0f);
        float varl = sq * (1.0f / 64.0f) - mu * mu;
        float ln = (a - mu) * rsqrtf(varl + 1e-5f) * wsf[OFF_LG + l] + wsf[OFF_LBN + l];
        if (active) {
            long idx = (long)n * 64 + l;
            float res = xrow[w][l] + fmaxf(ln, 0.f);
            if (mode == 0) ((u16*)outp)[idx] = f2bf(res);
            else           ((float*)outp)[idx] = res;
        }
    }
}

extern "C" void kernel_launch(void* const* d_in, const int* in_sizes, int n_in,
                              void* d_out, int out_size, void* d_ws, size_t ws_size,
                              hipStream_t stream) {
    const void* atom_x   = d_in[0];
    const void* bond_emb = d_in[1];
    const void* edge_w   = d_in[2];
    const void* edge_b   = d_in[3];
    const void* pre_w1   = d_in[4];
    const void* pre_b1   = d_in[5];
    const void* pre_w2   = d_in[6];
    const void* pre_b2   = d_in[7];
    const void* post_w1  = d_in[8];
    const void* post_b1  = d_in[9];
    const void* post_w2  = d_in[10];
    const void* post_b2  = d_in[11];
    const void* lin_w    = d_in[12];
    const void* lin_b    = d_in[13];
    const void* ln_g     = d_in[14];
    const void* ln_b     = d_in[15];
    const int* bond_x    = (const int*)d_in[16];
    const int* aei       = (const int*)d_in[17];

    int E  = in_sizes[16];
    int Nn = in_sizes[0] / 64;
    const int* srcp = aei;
    const int* dstp = aei + E;

    float* wsf = (float*)d_ws;
    int*   wsi = (int*)d_ws;

    size_t o = IB;
    int* modep = wsi + o; o += 16;
    int* cnt   = wsi + o; o += Nn;
    o = (o + 63) & ~(size_t)63;
    int* pk    = wsi + o; o += (size_t)Nn * MAXD;
    float* Yp  = (float*)(wsi + o); o += (size_t)Nn * 64;
    float* XWp = (float*)(wsi + o); o += (size_t)Nn * 64;
    // ws usage ~39 MB

    const int NIB  = 1600;
    const int SBLK = (E + 255) / 256;

    (void)hipMemsetAsync(cnt, 0, (size_t)Nn * sizeof(int), stream);
    k_prep<<<NIB + SBLK, 256, 0, stream>>>(dstp, srcp, bond_x,
                                           bond_emb, edge_w, edge_b,
                                           pre_w1, pre_b1, pre_w2, pre_b2,
                                           post_w1, post_b1, post_w2, post_b2,
                                           lin_w, lin_b, ln_g, ln_b,
                                           atom_x, wsf, Yp, XWp, cnt, pk, modep, Nn, E, NIB);
    dim3 gn((Nn + 3) / 4, 1, 1);
    k_node<<<gn, 256, 0, stream>>>(atom_x, Yp, XWp, pk, cnt, wsf, d_out, modep, Nn);
}

// Round 5
// 298.924 us; speedup vs baseline: 1.0339x; 1.0305x over previous
//
#include <hip/hip_runtime.h>
#include <cstdint>

typedef unsigned short u16;

#define AVG_LOG_F 1.4862356961977451f
#define MAXD 64

// ---- workspace float-unit offsets (weights region) ----
#define OFF_W2   3072   // pre_w2  fp32 [4][16][16]
#define OFF_PW1  4096   // post_w1 fp32 [4][256][16]
#define OFF_PW2  20480  // post_w2 fp32 [4][16][16]
#define OFF_LW   21504  // lin_w   fp32 [64][64]
#define OFF_PB1  25600
#define OFF_PB2  25664
#define OFF_QB1  25728
#define OFF_QB2  25792
#define OFF_LB   25856
#define OFF_LG   25920
#define OFF_LBN  25984
#define OFF_EWT  26128  // eWtab  fp32 [5][64]  (pb1 + ET.W1e, node-invariant)
#define IB       26448  // int region start (4B units)

__device__ __forceinline__ float bf2f(u16 u) {
    return __uint_as_float(((unsigned)u) << 16);
}
__device__ __forceinline__ u16 f2bf(float f) {
    unsigned u = __float_as_uint(f);
    u += 0x7fffu + ((u >> 16) & 1u);
    return (u16)(u >> 16);
}
__device__ __forceinline__ float rdin(const void* p, long j, int mode) {
    if (mode == 0) return bf2f(((const u16*)p)[j]);
    return ((const float*)p)[j];
}
template <int MODE>
__device__ __forceinline__ void load16c(const void* p, long base, float* o) {
    if (MODE == 0) {
        const u16* q = (const u16*)p + base;
        uint4 a = *(const uint4*)q;
        uint4 b = *(const uint4*)(q + 8);
        o[0]  = __uint_as_float(a.x << 16); o[1]  = __uint_as_float(a.x & 0xffff0000u);
        o[2]  = __uint_as_float(a.y << 16); o[3]  = __uint_as_float(a.y & 0xffff0000u);
        o[4]  = __uint_as_float(a.z << 16); o[5]  = __uint_as_float(a.z & 0xffff0000u);
        o[6]  = __uint_as_float(a.w << 16); o[7]  = __uint_as_float(a.w & 0xffff0000u);
        o[8]  = __uint_as_float(b.x << 16); o[9]  = __uint_as_float(b.x & 0xffff0000u);
        o[10] = __uint_as_float(b.y << 16); o[11] = __uint_as_float(b.y & 0xffff0000u);
        o[12] = __uint_as_float(b.z << 16); o[13] = __uint_as_float(b.z & 0xffff0000u);
        o[14] = __uint_as_float(b.w << 16); o[15] = __uint_as_float(b.w & 0xffff0000u);
    } else {
        const float* q = (const float*)p + base;
        float4 a = *(const float4*)q;
        float4 b = *(const float4*)(q + 4);
        float4 c = *(const float4*)(q + 8);
        float4 d = *(const float4*)(q + 12);
        o[0]=a.x; o[1]=a.y; o[2]=a.z; o[3]=a.w;
        o[4]=b.x; o[5]=b.y; o[6]=b.z; o[7]=b.w;
        o[8]=c.x; o[9]=c.y; o[10]=c.z; o[11]=c.w;
        o[12]=d.x; o[13]=d.y; o[14]=d.z; o[15]=d.w;
    }
}

// per-node precompute: Y[n][l] = x[n].W1_xj column,  XW[n][l] = x[n].W1_xi column
template <int MODE>
__device__ __forceinline__ void y_loop(const void* ax, const void* pre_w1, float* wsY, float* wsXW,
                                       int Nn, int wave, int nwaves, int l) {
    const int t = l >> 4, g = l & 15;
    float wxi[16], wxj[16];
#pragma unroll
    for (int f = 0; f < 16; f++) {
        wxi[f] = rdin(pre_w1, t * 768 + f * 16 + g, MODE);
        wxj[f] = rdin(pre_w1, t * 768 + (16 + f) * 16 + g, MODE);
    }
    for (int n = wave; n < Nn; n += nwaves) {
        float xj[16];
        load16c<MODE>(ax, (long)n * 64 + t * 16, xj);
        float accY = 0.f, accX = 0.f;
#pragma unroll
        for (int f = 0; f < 16; f++) {
            accY = fmaf(xj[f], wxj[f], accY);
            accX = fmaf(xj[f], wxi[f], accX);
        }
        wsY[(long)n * 64 + l]  = accY;
        wsXW[(long)n * 64 + l] = accX;
    }
}

// ---------------- 1: fused prep: weights->fp32, ET/eWtab, Y/XW precompute, edge scatter ----
__global__ __launch_bounds__(256) void k_prep(
    const int* __restrict__ dstp, const int* __restrict__ srcp, const int* __restrict__ bondp,
    const void* bond_emb, const void* edge_w, const void* edge_b,
    const void* pre_w1, const void* pre_b1, const void* pre_w2, const void* pre_b2,
    const void* post_w1, const void* post_b1, const void* post_w2, const void* post_b2,
    const void* lin_w, const void* lin_b, const void* ln_g, const void* ln_b,
    const void* ax, float* wsf, float* wsY, float* wsXW,
    int* __restrict__ cnt, int* __restrict__ pk, int* modep,
    int Nn, int E, int NIB)
{
    int tid = threadIdx.x;
    if ((int)blockIdx.x >= NIB) {            // ---- scatter part ----
        int e = ((int)blockIdx.x - NIB) * 256 + tid;
        if (e < E) {
            int d = dstp[e];
            int pos = atomicAdd(&cnt[d], 1);
            // pack (src*64)<<3 | bond  ->  k_node row offset = (v>>3)+l, bond = v&7
            if (pos < MAXD) pk[d * MAXD + pos] = (srcp[e] << 9) | (bondp[e] & 7);
        }
        return;
    }
    // ---- init part ----
    __shared__ int csh;
    __shared__ float ET[80];
    if (tid == 0) csh = 0;
    __syncthreads();
    {
        unsigned v = ((const unsigned*)ax)[tid];
        unsigned lo = v & 0xffffu;
        int ee = (int)((lo >> 7) & 0xff);
        int isbf = (lo == 0u) || (ee >= 110 && ee <= 140);
        atomicAdd(&csh, isbf);
    }
    __syncthreads();
    int mode = (csh >= 192) ? 0 : 1;

    int b = (int)blockIdx.x;
    int gt = b * 256 + tid;
    int gs = NIB * 256;
    if (b == 0 && tid == 0) modep[0] = mode;

    for (int j = gt; j < 1024; j += gs)  wsf[OFF_W2 + j]  = rdin(pre_w2, j, mode);
    for (int j = gt; j < 16384; j += gs) wsf[OFF_PW1 + j] = rdin(post_w1, j, mode);
    for (int j = gt; j < 1024; j += gs)  wsf[OFF_PW2 + j] = rdin(post_w2, j, mode);
    for (int j = gt; j < 4096; j += gs)  wsf[OFF_LW + j]  = rdin(lin_w, j, mode);
    for (int j = gt; j < 64; j += gs) {
        wsf[OFF_PB1 + j] = rdin(pre_b1, j, mode);
        wsf[OFF_PB2 + j] = rdin(pre_b2, j, mode);
        wsf[OFF_QB1 + j] = rdin(post_b1, j, mode);
        wsf[OFF_QB2 + j] = rdin(post_b2, j, mode);
        wsf[OFF_LB + j]  = rdin(lin_b, j, mode);
        wsf[OFF_LG + j]  = rdin(ln_g, j, mode);
        wsf[OFF_LBN + j] = rdin(ln_b, j, mode);
    }
    if (b == 0) {
        if (tid < 80) {
            int bb = tid >> 4, f = tid & 15;
            float acc = rdin(edge_b, f, mode);
            for (int k = 0; k < 64; k++)
                acc = fmaf(rdin(bond_emb, bb * 64 + k, mode), rdin(edge_w, k * 16 + f, mode), acc);
            ET[tid] = acc;
        }
        __syncthreads();
        for (int j = tid; j < 320; j += 256) {
            int bb = j >> 6, ll = j & 63, tt = ll >> 4, gg = ll & 15;
            float acc = rdin(pre_b1, tt * 16 + gg, mode);
#pragma unroll
            for (int f = 0; f < 16; f++)
                acc = fmaf(ET[bb * 16 + f], rdin(pre_w1, tt * 768 + (32 + f) * 16 + gg, mode), acc);
            wsf[OFF_EWT + j] = acc;
        }
    }
    int wave = gt >> 6;
    int nwaves = gs >> 6;
    int l = tid & 63;
    if (mode == 0) y_loop<0>(ax, pre_w1, wsY, wsXW, Nn, wave, nwaves, l);
    else           y_loop<1>(ax, pre_w1, wsY, wsXW, Nn, wave, nwaves, l);
}

// ---------------- 2: fused node kernel: DPP-rotation matvec, zero LDS in edge loop --------
// Per-edge W2 matvec done with row_ror:r DPP rotations within 16-lane tower groups:
// m[l] = pb2g + sum_r rot16(h,r) * w2r[r], w2r pre-permuted per-lane. No hb round-trip.
__global__ __launch_bounds__(256, 4) void k_node(
    const void* __restrict__ ax, const float* __restrict__ Yp, const float* __restrict__ XWp,
    const int* __restrict__ pk, const int* __restrict__ cnt,
    const float* __restrict__ wsf, void* __restrict__ outp,
    const int* __restrict__ modep, int Nn)
{
    __shared__ float hb[4][8][64];       // stats[0..4], p1[5], p2[6]
    __shared__ float zws[4][5][64];
    __shared__ float qp[4][4][64];       // [wave][node][chan] partials (scalers folded)
    __shared__ float xrow[4][64];        // x_i rows (also residual source)
    __shared__ float scl1s[4], scl2s[4];
    const int w = threadIdx.x >> 6;
    const int l = threadIdx.x & 63;
    const int t = l >> 4;
    const int g = l & 15;
    const int n = blockIdx.x * 4 + w;
    const int mode = modep[0];
    const bool active = (n < Nn);
    const int nn = active ? n : 0;

    const float* W2  = wsf + OFF_W2  + t * 256;
    const float* PW1 = wsf + OFF_PW1 + t * 4096;
    const float* PW2 = wsf + OFF_PW2 + t * 256;

    // ---- DPP row_ror orientation self-probe (avoids spec-orientation gamble) ----
    // After row_ror:1, lane l holds value from lane (l+dir)&15 of its row.
    int probe = __builtin_amdgcn_update_dpp(0, l & 15, 0x121, 0xf, 0xf, false);
    int p0 = __builtin_amdgcn_readfirstlane(probe);
    const int dir = (p0 == 1) ? 1 : -1;

    // w2r[r] = W2[sigma_r(g)][g] where sigma_r(g) = (g + dir*r) & 15
    float w2r[16];
#pragma unroll
    for (int r = 0; r < 16; r++) w2r[r] = W2[((g + dir * r) & 15) * 16 + g];

    float pb2g = wsf[OFF_PB2 + t * 16 + g];
    float qb1g = wsf[OFF_QB1 + t * 16 + g];
    float qb2g = wsf[OFF_QB2 + t * 16 + g];

    int deg = active ? cnt[nn] : 0;
    if (deg > MAXD) deg = MAXD;

    int   pkvAll = pk[nn * MAXD + l];
    float XWv    = XWp[(long)nn * 64 + l];
    zws[w][0][l] = XWv + wsf[OFF_EWT + 0 * 64 + l];
    zws[w][1][l] = XWv + wsf[OFF_EWT + 1 * 64 + l];
    zws[w][2][l] = XWv + wsf[OFF_EWT + 2 * 64 + l];
    zws[w][3][l] = XWv + wsf[OFF_EWT + 3 * 64 + l];
    zws[w][4][l] = XWv + wsf[OFF_EWT + 4 * 64 + l];
    xrow[w][l]   = rdin(ax, (long)nn * 64 + l, mode);

    float s = 0.f, s2 = 0.f, mn = 3.0e38f, mx = -3.0e38f;

#define ROTFMA(r, ctrl)                                                              \
    {                                                                                \
        int tmp_ = __builtin_amdgcn_update_dpp(0, hi, ctrl, 0xf, 0xf, false);        \
        float hv_ = __int_as_float(tmp_);                                            \
        if ((r) & 1) mb = fmaf(hv_, w2r[r], mb);                                     \
        else         ma = fmaf(hv_, w2r[r], ma);                                     \
    }

    // wave-uniform deg -> uniform branches, no divergence; batches of 8 for load MLP
    for (int kb = 0; kb < deg; kb += 8) {
        float yv[8];
        int   vs[8];
#pragma unroll
        for (int k = 0; k < 8; k++) {
            if (kb + k < deg) {
                vs[k] = __builtin_amdgcn_readlane(pkvAll, kb + k);
                yv[k] = Yp[(vs[k] >> 3) + l];
            }
        }
#pragma unroll
        for (int k = 0; k < 8; k++) {
            if (kb + k < deg) {
                float h = fmaxf(yv[k] + zws[w][vs[k] & 7][l], 0.f);
                int hi = __float_as_uint(h);
                float ma = fmaf(h, w2r[0], pb2g);
                float mb = 0.f;
                ROTFMA(1, 0x121);  ROTFMA(2, 0x122);  ROTFMA(3, 0x123);
                ROTFMA(4, 0x124);  ROTFMA(5, 0x125);  ROTFMA(6, 0x126);
                ROTFMA(7, 0x127);  ROTFMA(8, 0x128);  ROTFMA(9, 0x129);
                ROTFMA(10, 0x12A); ROTFMA(11, 0x12B); ROTFMA(12, 0x12C);
                ROTFMA(13, 0x12D); ROTFMA(14, 0x12E); ROTFMA(15, 0x12F);
                float m = ma + mb;
                s += m;
                s2 = fmaf(m, m, s2);
                mn = fminf(mn, m);
                mx = fmaxf(mx, m);
            }
        }
    }
#undef ROTFMA

    if (deg == 0) { mn = 0.f; mx = 0.f; }
    float cf = (float)(deg > 0 ? deg : 1);
    float inv = 1.0f / cf;
    float mean = s * inv;
    float var = s2 * inv - mean * mean;
    float sd = sqrtf(fmaxf(var, 0.f) + 1e-5f);
    float ldv = logf(cf + 1.0f);
    float sc1 = ldv * (1.0f / AVG_LOG_F);
    float sc2 = AVG_LOG_F / ldv;

    hb[w][0][l] = s;
    hb[w][1][l] = mean;
    hb[w][2][l] = mn;
    hb[w][3][l] = mx;
    hb[w][4][l] = sd;
    if (l == 0) { scl1s[w] = sc1; scl2s[w] = sc2; }
    __syncthreads();

    // ---- co-computed post-MLP layer 1: this wave handles f in [4w, 4w+4) for ALL 4 nodes;
    //      3 degree-scaler variants folded at write using each node's scalers.
    const int F0 = w * 4;
    float q0[4] = {0,0,0,0}, q1[4] = {0,0,0,0}, q2[4] = {0,0,0,0};
    {
        float xa[4][4];
#pragma unroll
        for (int nd = 0; nd < 4; nd++) {
            float4 v = *(const float4*)&xrow[nd][t * 16 + F0];
            xa[nd][0] = v.x; xa[nd][1] = v.y; xa[nd][2] = v.z; xa[nd][3] = v.w;
        }
#pragma unroll
        for (int fi = 0; fi < 4; fi++) {
            float wv = PW1[(F0 + fi) * 16 + g];
#pragma unroll
            for (int nd = 0; nd < 4; nd++) q0[nd] = fmaf(xa[nd][fi], wv, q0[nd]);
        }
    }
#pragma unroll
    for (int a = 0; a < 5; a++) {
        float xa[4][4];
#pragma unroll
        for (int nd = 0; nd < 4; nd++) {
            float4 v = *(const float4*)&hb[nd][a][t * 16 + F0];
            xa[nd][0] = v.x; xa[nd][1] = v.y; xa[nd][2] = v.z; xa[nd][3] = v.w;
        }
        const int rb = 16 + a * 16;
#pragma unroll
        for (int fi = 0; fi < 4; fi++) {
            const int r = (rb + F0 + fi) * 16 + g;
            float w0  = PW1[r];
            float w1  = PW1[r + 80 * 16];
            float w2v = PW1[r + 160 * 16];
#pragma unroll
            for (int nd = 0; nd < 4; nd++) {
                float x = xa[nd][fi];
                q0[nd] = fmaf(x, w0,  q0[nd]);
                q1[nd] = fmaf(x, w1,  q1[nd]);
                q2[nd] = fmaf(x, w2v, q2[nd]);
            }
        }
    }
#pragma unroll
    for (int nd = 0; nd < 4; nd++)
        qp[w][nd][l] = fmaf(scl2s[nd], q2[nd], fmaf(scl1s[nd], q1[nd], q0[nd]));
    __syncthreads();

    // ---- own-node combine + layer 2 ----
    {
        float q0s = qp[0][w][l] + qp[1][w][l] + qp[2][w][l] + qp[3][w][l];
        float p1 = fmaxf(q0s + qb1g, 0.f);
        hb[w][5][l] = p1;
        float pw2c[16];
#pragma unroll
        for (int f = 0; f < 16; f++) pw2c[f] = PW2[f * 16 + g];
        float m2 = qb2g;
        const float4* pp = (const float4*)&hb[w][5][t * 16];
        float4 p0v = pp[0], r1 = pp[1], r2 = pp[2], r3 = pp[3];
        m2 = fmaf(p0v.x, pw2c[0],  m2); m2 = fmaf(p0v.y, pw2c[1],  m2);
        m2 = fmaf(p0v.z, pw2c[2],  m2); m2 = fmaf(p0v.w, pw2c[3],  m2);
        m2 = fmaf(r1.x, pw2c[4],  m2); m2 = fmaf(r1.y, pw2c[5],  m2);
        m2 = fmaf(r1.z, pw2c[6],  m2); m2 = fmaf(r1.w, pw2c[7],  m2);
        m2 = fmaf(r2.x, pw2c[8],  m2); m2 = fmaf(r2.y, pw2c[9],  m2);
        m2 = fmaf(r2.z, pw2c[10], m2); m2 = fmaf(r2.w, pw2c[11], m2);
        m2 = fmaf(r3.x, pw2c[12], m2); m2 = fmaf(r3.y, pw2c[13], m2);
        m2 = fmaf(r3.z, pw2c[14], m2); m2 = fmaf(r3.w, pw2c[15], m2);
        hb[w][6][l] = m2;
    }
    __syncthreads();

    // ---- co-computed final 64x64 linear: this wave handles f in [16w, 16w+16) for 4 nodes
    {
        const float* LW = wsf + OFF_LW;
        const int fb = w * 16;
        float lw[4] = {0,0,0,0};
#pragma unroll
        for (int c = 0; c < 4; c++) {
            float pa[4][4];
#pragma unroll
            for (int nd = 0; nd < 4; nd++) {
                float4 v = *(const float4*)&hb[nd][6][fb + 4 * c];
                pa[nd][0] = v.x; pa[nd][1] = v.y; pa[nd][2] = v.z; pa[nd][3] = v.w;
            }
#pragma unroll
            for (int fi = 0; fi < 4; fi++) {
                float wl = LW[(fb + 4 * c + fi) * 64 + l];
#pragma unroll
                for (int nd = 0; nd < 4; nd++) lw[nd] = fmaf(pa[nd][fi], wl, lw[nd]);
            }
        }
#pragma unroll
        for (int nd = 0; nd < 4; nd++) qp[w][nd][l] = lw[nd];
    }
    __syncthreads();

    // ---- own-node LayerNorm + ReLU + residual ----
    {
        float a = wsf[OFF_LB + l] + qp[0][w][l] + qp[1][w][l] + qp[2][w][l] + qp[3][w][l];
        float s1 = a, sq = a * a;
#pragma unroll
        for (int o = 1; o < 64; o <<= 1) { s1 += __shfl_xor(s1, o); sq += __shfl_xor(sq, o); }
        float mu = s1 * (1.0f / 64.0f);
        float varl = sq * (1.0f / 64.0f) - mu * mu;
        float ln = (a - mu) * rsqrtf(varl + 1e-5f) * wsf[OFF_LG + l] + wsf[OFF_LBN + l];
        if (active) {
            long idx = (long)n * 64 + l;
            float res = xrow[w][l] + fmaxf(ln, 0.f);
            if (mode == 0) ((u16*)outp)[idx] = f2bf(res);
            else           ((float*)outp)[idx] = res;
        }
    }
}

extern "C" void kernel_launch(void* const* d_in, const int* in_sizes, int n_in,
                              void* d_out, int out_size, void* d_ws, size_t ws_size,
                              hipStream_t stream) {
    const void* atom_x   = d_in[0];
    const void* bond_emb = d_in[1];
    const void* edge_w   = d_in[2];
    const void* edge_b   = d_in[3];
    const void* pre_w1   = d_in[4];
    const void* pre_b1   = d_in[5];
    const void* pre_w2   = d_in[6];
    const void* pre_b2   = d_in[7];
    const void* post_w1  = d_in[8];
    const void* post_b1  = d_in[9];
    const void* post_w2  = d_in[10];
    const void* post_b2  = d_in[11];
    const void* lin_w    = d_in[12];
    const void* lin_b    = d_in[13];
    const void* ln_g     = d_in[14];
    const void* ln_b     = d_in[15];
    const int* bond_x    = (const int*)d_in[16];
    const int* aei       = (const int*)d_in[17];

    int E  = in_sizes[16];
    int Nn = in_sizes[0] / 64;
    const int* srcp = aei;
    const int* dstp = aei + E;

    float* wsf = (float*)d_ws;
    int*   wsi = (int*)d_ws;

    size_t o = IB;
    int* modep = wsi + o; o += 16;
    int* cnt   = wsi + o; o += Nn;
    o = (o + 63) & ~(size_t)63;
    int* pk    = wsi + o; o += (size_t)Nn * MAXD;
    float* Yp  = (float*)(wsi + o); o += (size_t)Nn * 64;
    float* XWp = (float*)(wsi + o); o += (size_t)Nn * 64;
    // ws usage ~39 MB

    const int NIB  = 1600;
    const int SBLK = (E + 255) / 256;

    (void)hipMemsetAsync(cnt, 0, (size_t)Nn * sizeof(int), stream);
    k_prep<<<NIB + SBLK, 256, 0, stream>>>(dstp, srcp, bond_x,
                                           bond_emb, edge_w, edge_b,
                                           pre_w1, pre_b1, pre_w2, pre_b2,
                                           post_w1, post_b1, post_w2, post_b2,
                                           lin_w, lin_b, ln_g, ln_b,
                                           atom_x, wsf, Yp, XWp, cnt, pk, modep, Nn, E, NIB);
    dim3 gn((Nn + 3) / 4, 1, 1);
    k_node<<<gn, 256, 0, stream>>>(atom_x, Yp, XWp, pk, cnt, wsf, d_out, modep, Nn);
}

// Round 6
// 285.783 us; speedup vs baseline: 1.0815x; 1.0460x over previous
//
#include <hip/hip_runtime.h>
#include <cstdint>

typedef unsigned short u16;
typedef _Float16 h2 __attribute__((ext_vector_type(2)));

#define AVG_LOG_F 1.4862356961977451f
#define MAXD 64

// ---- workspace float-unit offsets (weights region) ----
#define OFF_W2   3072   // pre_w2  fp32 [4][16][16]
#define OFF_PW1  4096   // post_w1 fp32 [4][256][16]
#define OFF_PW2  20480  // post_w2 fp32 [4][16][16]
#define OFF_LW   21504  // lin_w   fp32 [64][64]
#define OFF_PB1  25600
#define OFF_PB2  25664
#define OFF_QB1  25728
#define OFF_QB2  25792
#define OFF_LB   25856
#define OFF_LG   25920
#define OFF_LBN  25984
#define OFF_EWT  26128  // eWtab  fp32 [5][64]  (pb1 + ET.W1e, node-invariant)
#define IB       26448  // int region start (4B units)

__device__ __forceinline__ float bf2f(u16 u) {
    return __uint_as_float(((unsigned)u) << 16);
}
__device__ __forceinline__ u16 f2bf(float f) {
    unsigned u = __float_as_uint(f);
    u += 0x7fffu + ((u >> 16) & 1u);
    return (u16)(u >> 16);
}
__device__ __forceinline__ float rdin(const void* p, long j, int mode) {
    if (mode == 0) return bf2f(((const u16*)p)[j]);
    return ((const float*)p)[j];
}
template <int MODE>
__device__ __forceinline__ void load16c(const void* p, long base, float* o) {
    if (MODE == 0) {
        const u16* q = (const u16*)p + base;
        uint4 a = *(const uint4*)q;
        uint4 b = *(const uint4*)(q + 8);
        o[0]  = __uint_as_float(a.x << 16); o[1]  = __uint_as_float(a.x & 0xffff0000u);
        o[2]  = __uint_as_float(a.y << 16); o[3]  = __uint_as_float(a.y & 0xffff0000u);
        o[4]  = __uint_as_float(a.z << 16); o[5]  = __uint_as_float(a.z & 0xffff0000u);
        o[6]  = __uint_as_float(a.w << 16); o[7]  = __uint_as_float(a.w & 0xffff0000u);
        o[8]  = __uint_as_float(b.x << 16); o[9]  = __uint_as_float(b.x & 0xffff0000u);
        o[10] = __uint_as_float(b.y << 16); o[11] = __uint_as_float(b.y & 0xffff0000u);
        o[12] = __uint_as_float(b.z << 16); o[13] = __uint_as_float(b.z & 0xffff0000u);
        o[14] = __uint_as_float(b.w << 16); o[15] = __uint_as_float(b.w & 0xffff0000u);
    } else {
        const float* q = (const float*)p + base;
        float4 a = *(const float4*)q;
        float4 b = *(const float4*)(q + 4);
        float4 c = *(const float4*)(q + 8);
        float4 d = *(const float4*)(q + 12);
        o[0]=a.x; o[1]=a.y; o[2]=a.z; o[3]=a.w;
        o[4]=b.x; o[5]=b.y; o[6]=b.z; o[7]=b.w;
        o[8]=c.x; o[9]=c.y; o[10]=c.z; o[11]=c.w;
        o[12]=d.x; o[13]=d.y; o[14]=d.z; o[15]=d.w;
    }
}

// per-node precompute: Y[n][l] = x[n].W1_xj column,  XW[n][l] = x[n].W1_xi column
template <int MODE>
__device__ __forceinline__ void y_loop(const void* ax, const void* pre_w1, float* wsY, float* wsXW,
                                       int Nn, int wave, int nwaves, int l) {
    const int t = l >> 4, g = l & 15;
    float wxi[16], wxj[16];
#pragma unroll
    for (int f = 0; f < 16; f++) {
        wxi[f] = rdin(pre_w1, t * 768 + f * 16 + g, MODE);
        wxj[f] = rdin(pre_w1, t * 768 + (16 + f) * 16 + g, MODE);
    }
    for (int n = wave; n < Nn; n += nwaves) {
        float xj[16];
        load16c<MODE>(ax, (long)n * 64 + t * 16, xj);
        float accY = 0.f, accX = 0.f;
#pragma unroll
        for (int f = 0; f < 16; f++) {
            accY = fmaf(xj[f], wxj[f], accY);
            accX = fmaf(xj[f], wxi[f], accX);
        }
        wsY[(long)n * 64 + l]  = accY;
        wsXW[(long)n * 64 + l] = accX;
    }
}

// ---------------- 1: fused prep: weights->fp32, ET/eWtab, Y/XW precompute, edge scatter ----
__global__ __launch_bounds__(256) void k_prep(
    const int* __restrict__ dstp, const int* __restrict__ srcp, const int* __restrict__ bondp,
    const void* bond_emb, const void* edge_w, const void* edge_b,
    const void* pre_w1, const void* pre_b1, const void* pre_w2, const void* pre_b2,
    const void* post_w1, const void* post_b1, const void* post_w2, const void* post_b2,
    const void* lin_w, const void* lin_b, const void* ln_g, const void* ln_b,
    const void* ax, float* wsf, float* wsY, float* wsXW,
    int* __restrict__ cnt, int* __restrict__ pk, int* modep,
    int Nn, int E, int NIB)
{
    int tid = threadIdx.x;
    if ((int)blockIdx.x >= NIB) {            // ---- scatter part ----
        int e = ((int)blockIdx.x - NIB) * 256 + tid;
        if (e < E) {
            int d = dstp[e];
            int pos = atomicAdd(&cnt[d], 1);
            // pack (src*64)<<3 | bond  ->  k_node row offset = (v>>3)+l, bond = v&7
            if (pos < MAXD) pk[d * MAXD + pos] = (srcp[e] << 9) | (bondp[e] & 7);
        }
        return;
    }
    // ---- init part ----
    __shared__ int csh;
    __shared__ float ET[80];
    if (tid == 0) csh = 0;
    __syncthreads();
    {
        unsigned v = ((const unsigned*)ax)[tid];
        unsigned lo = v & 0xffffu;
        int ee = (int)((lo >> 7) & 0xff);
        int isbf = (lo == 0u) || (ee >= 110 && ee <= 140);
        atomicAdd(&csh, isbf);
    }
    __syncthreads();
    int mode = (csh >= 192) ? 0 : 1;

    int b = (int)blockIdx.x;
    int gt = b * 256 + tid;
    int gs = NIB * 256;
    if (b == 0 && tid == 0) modep[0] = mode;

    for (int j = gt; j < 1024; j += gs)  wsf[OFF_W2 + j]  = rdin(pre_w2, j, mode);
    for (int j = gt; j < 16384; j += gs) wsf[OFF_PW1 + j] = rdin(post_w1, j, mode);
    for (int j = gt; j < 1024; j += gs)  wsf[OFF_PW2 + j] = rdin(post_w2, j, mode);
    for (int j = gt; j < 4096; j += gs)  wsf[OFF_LW + j]  = rdin(lin_w, j, mode);
    for (int j = gt; j < 64; j += gs) {
        wsf[OFF_PB1 + j] = rdin(pre_b1, j, mode);
        wsf[OFF_PB2 + j] = rdin(pre_b2, j, mode);
        wsf[OFF_QB1 + j] = rdin(post_b1, j, mode);
        wsf[OFF_QB2 + j] = rdin(post_b2, j, mode);
        wsf[OFF_LB + j]  = rdin(lin_b, j, mode);
        wsf[OFF_LG + j]  = rdin(ln_g, j, mode);
        wsf[OFF_LBN + j] = rdin(ln_b, j, mode);
    }
    if (b == 0) {
        if (tid < 80) {
            int bb = tid >> 4, f = tid & 15;
            float acc = rdin(edge_b, f, mode);
            for (int k = 0; k < 64; k++)
                acc = fmaf(rdin(bond_emb, bb * 64 + k, mode), rdin(edge_w, k * 16 + f, mode), acc);
            ET[tid] = acc;
        }
        __syncthreads();
        for (int j = tid; j < 320; j += 256) {
            int bb = j >> 6, ll = j & 63, tt = ll >> 4, gg = ll & 15;
            float acc = rdin(pre_b1, tt * 16 + gg, mode);
#pragma unroll
            for (int f = 0; f < 16; f++)
                acc = fmaf(ET[bb * 16 + f], rdin(pre_w1, tt * 768 + (32 + f) * 16 + gg, mode), acc);
            wsf[OFF_EWT + j] = acc;
        }
    }
    int wave = gt >> 6;
    int nwaves = gs >> 6;
    int l = tid & 63;
    if (mode == 0) y_loop<0>(ax, pre_w1, wsY, wsXW, Nn, wave, nwaves, l);
    else           y_loop<1>(ax, pre_w1, wsY, wsXW, Nn, wave, nwaves, l);
}

// ---------------- 2: fused node kernel: f16 message buffer + v_dot2_f32_f16 matvec -------
// Per-edge: h stored in LDS as f16 (half the ds_read bytes), 16x16 W2 matvec done as
// 8x v_dot2_f32_f16 (2 MACs/inst, fp32 accum) with pre-packed half2 W2 columns.
__global__ __launch_bounds__(256, 4) void k_node(
    const void* __restrict__ ax, const float* __restrict__ Yp, const float* __restrict__ XWp,
    const int* __restrict__ pk, const int* __restrict__ cnt,
    const float* __restrict__ wsf, void* __restrict__ outp,
    const int* __restrict__ modep, int Nn)
{
    __shared__ float hb[4][8][64];       // stats[0..4], p1[5], p2[6]
    __shared__ _Float16 hbh[4][8][64];   // f16 message batch buffer (8 edges deep)
    __shared__ float zws[4][5][64];
    __shared__ float qp[4][4][64];       // [wave][node][chan] partials (scalers folded)
    __shared__ float xrow[4][64];        // x_i rows (also residual source)
    __shared__ float scl1s[4], scl2s[4];
    const int w = threadIdx.x >> 6;
    const int l = threadIdx.x & 63;
    const int t = l >> 4;
    const int g = l & 15;
    const int n = blockIdx.x * 4 + w;
    const int mode = modep[0];
    const bool active = (n < Nn);
    const int nn = active ? n : 0;

    const float* W2  = wsf + OFF_W2  + t * 256;
    const float* PW1 = wsf + OFF_PW1 + t * 4096;
    const float* PW2 = wsf + OFF_PW2 + t * 256;

    // pre-packed half2 W2 column for lane's output g: w2h[i] = (W2[2i][g], W2[2i+1][g])
    h2 w2h[8];
#pragma unroll
    for (int i = 0; i < 8; i++) {
        h2 p; p.x = (_Float16)W2[(2 * i) * 16 + g]; p.y = (_Float16)W2[(2 * i + 1) * 16 + g];
        w2h[i] = p;
    }
    float pb2g = wsf[OFF_PB2 + t * 16 + g];
    float qb1g = wsf[OFF_QB1 + t * 16 + g];
    float qb2g = wsf[OFF_QB2 + t * 16 + g];

    int deg = active ? cnt[nn] : 0;
    if (deg > MAXD) deg = MAXD;

    int   pkvAll = pk[nn * MAXD + l];
    float XWv    = XWp[(long)nn * 64 + l];
    zws[w][0][l] = XWv + wsf[OFF_EWT + 0 * 64 + l];
    zws[w][1][l] = XWv + wsf[OFF_EWT + 1 * 64 + l];
    zws[w][2][l] = XWv + wsf[OFF_EWT + 2 * 64 + l];
    zws[w][3][l] = XWv + wsf[OFF_EWT + 3 * 64 + l];
    zws[w][4][l] = XWv + wsf[OFF_EWT + 4 * 64 + l];
    xrow[w][l]   = rdin(ax, (long)nn * 64 + l, mode);

    float s = 0.f, s2 = 0.f, mn = 3.0e38f, mx = -3.0e38f;

    // matvec for one buffered edge row: m = pb2g + sum_i dot2(h2 pair, w2 pair)
    auto phaseB = [&](int k) {
        const uint4* hp = (const uint4*)&hbh[w][k][t * 16];   // 32B = 2x ds_read_b128
        uint4 u0 = hp[0], u1 = hp[1];
        h2 hv[8];
        *(uint4*)&hv[0] = u0;
        *(uint4*)&hv[4] = u1;
        float m = __builtin_amdgcn_fdot2(hv[0], w2h[0], pb2g, false);
        m = __builtin_amdgcn_fdot2(hv[1], w2h[1], m, false);
        m = __builtin_amdgcn_fdot2(hv[2], w2h[2], m, false);
        m = __builtin_amdgcn_fdot2(hv[3], w2h[3], m, false);
        m = __builtin_amdgcn_fdot2(hv[4], w2h[4], m, false);
        m = __builtin_amdgcn_fdot2(hv[5], w2h[5], m, false);
        m = __builtin_amdgcn_fdot2(hv[6], w2h[6], m, false);
        m = __builtin_amdgcn_fdot2(hv[7], w2h[7], m, false);
        s += m;
        s2 = fmaf(m, m, s2);
        mn = fminf(mn, m);
        mx = fmaxf(mx, m);
    };

    for (int kb = 0; kb < deg; kb += 8) {
        int B = deg - kb; if (B > 8) B = 8;
        float yv[8]; int vs[8];
        if (B == 8) {
#pragma unroll
            for (int k = 0; k < 8; k++) {
                vs[k] = __builtin_amdgcn_readlane(pkvAll, kb + k);
                yv[k] = Yp[(vs[k] >> 3) + l];
            }
#pragma unroll
            for (int k = 0; k < 8; k++)
                hbh[w][k][l] = (_Float16)fmaxf(yv[k] + zws[w][vs[k] & 7][l], 0.f);
#pragma unroll
            for (int k = 0; k < 8; k++) phaseB(k);
        } else {
            for (int k = 0; k < B; k++) {
                vs[k] = __builtin_amdgcn_readlane(pkvAll, kb + k);
                yv[k] = Yp[(vs[k] >> 3) + l];
            }
            for (int k = 0; k < B; k++)
                hbh[w][k][l] = (_Float16)fmaxf(yv[k] + zws[w][vs[k] & 7][l], 0.f);
            for (int k = 0; k < B; k++) phaseB(k);
        }
    }

    if (deg == 0) { mn = 0.f; mx = 0.f; }
    float cf = (float)(deg > 0 ? deg : 1);
    float inv = 1.0f / cf;
    float mean = s * inv;
    float var = s2 * inv - mean * mean;
    float sd = sqrtf(fmaxf(var, 0.f) + 1e-5f);
    float ldv = logf(cf + 1.0f);
    float sc1 = ldv * (1.0f / AVG_LOG_F);
    float sc2 = AVG_LOG_F / ldv;

    hb[w][0][l] = s;
    hb[w][1][l] = mean;
    hb[w][2][l] = mn;
    hb[w][3][l] = mx;
    hb[w][4][l] = sd;
    if (l == 0) { scl1s[w] = sc1; scl2s[w] = sc2; }
    __syncthreads();

    // ---- co-computed post-MLP layer 1: this wave handles f in [4w, 4w+4) for ALL 4 nodes;
    //      3 degree-scaler variants folded at write using each node's scalers.
    const int F0 = w * 4;
    float q0[4] = {0,0,0,0}, q1[4] = {0,0,0,0}, q2[4] = {0,0,0,0};
    {
        float xa[4][4];
#pragma unroll
        for (int nd = 0; nd < 4; nd++) {
            float4 v = *(const float4*)&xrow[nd][t * 16 + F0];
            xa[nd][0] = v.x; xa[nd][1] = v.y; xa[nd][2] = v.z; xa[nd][3] = v.w;
        }
#pragma unroll
        for (int fi = 0; fi < 4; fi++) {
            float wv = PW1[(F0 + fi) * 16 + g];
#pragma unroll
            for (int nd = 0; nd < 4; nd++) q0[nd] = fmaf(xa[nd][fi], wv, q0[nd]);
        }
    }
#pragma unroll
    for (int a = 0; a < 5; a++) {
        float xa[4][4];
#pragma unroll
        for (int nd = 0; nd < 4; nd++) {
            float4 v = *(const float4*)&hb[nd][a][t * 16 + F0];
            xa[nd][0] = v.x; xa[nd][1] = v.y; xa[nd][2] = v.z; xa[nd][3] = v.w;
        }
        const int rb = 16 + a * 16;
#pragma unroll
        for (int fi = 0; fi < 4; fi++) {
            const int r = (rb + F0 + fi) * 16 + g;
            float w0  = PW1[r];
            float w1  = PW1[r + 80 * 16];
            float w2v = PW1[r + 160 * 16];
#pragma unroll
            for (int nd = 0; nd < 4; nd++) {
                float x = xa[nd][fi];
                q0[nd] = fmaf(x, w0,  q0[nd]);
                q1[nd] = fmaf(x, w1,  q1[nd]);
                q2[nd] = fmaf(x, w2v, q2[nd]);
            }
        }
    }
#pragma unroll
    for (int nd = 0; nd < 4; nd++)
        qp[w][nd][l] = fmaf(scl2s[nd], q2[nd], fmaf(scl1s[nd], q1[nd], q0[nd]));
    __syncthreads();

    // ---- own-node combine + layer 2 ----
    {
        float q0s = qp[0][w][l] + qp[1][w][l] + qp[2][w][l] + qp[3][w][l];
        float p1 = fmaxf(q0s + qb1g, 0.f);
        hb[w][5][l] = p1;
        float pw2c[16];
#pragma unroll
        for (int f = 0; f < 16; f++) pw2c[f] = PW2[f * 16 + g];
        float m2 = qb2g;
        const float4* pp = (const float4*)&hb[w][5][t * 16];
        float4 p0v = pp[0], r1 = pp[1], r2 = pp[2], r3 = pp[3];
        m2 = fmaf(p0v.x, pw2c[0],  m2); m2 = fmaf(p0v.y, pw2c[1],  m2);
        m2 = fmaf(p0v.z, pw2c[2],  m2); m2 = fmaf(p0v.w, pw2c[3],  m2);
        m2 = fmaf(r1.x, pw2c[4],  m2); m2 = fmaf(r1.y, pw2c[5],  m2);
        m2 = fmaf(r1.z, pw2c[6],  m2); m2 = fmaf(r1.w, pw2c[7],  m2);
        m2 = fmaf(r2.x, pw2c[8],  m2); m2 = fmaf(r2.y, pw2c[9],  m2);
        m2 = fmaf(r2.z, pw2c[10], m2); m2 = fmaf(r2.w, pw2c[11], m2);
        m2 = fmaf(r3.x, pw2c[12], m2); m2 = fmaf(r3.y, pw2c[13], m2);
        m2 = fmaf(r3.z, pw2c[14], m2); m2 = fmaf(r3.w, pw2c[15], m2);
        hb[w][6][l] = m2;
    }
    __syncthreads();

    // ---- co-computed final 64x64 linear: this wave handles f in [16w, 16w+16) for 4 nodes
    {
        const float* LW = wsf + OFF_LW;
        const int fb = w * 16;
        float lw[4] = {0,0,0,0};
#pragma unroll
        for (int c = 0; c < 4; c++) {
            float pa[4][4];
#pragma unroll
            for (int nd = 0; nd < 4; nd++) {
                float4 v = *(const float4*)&hb[nd][6][fb + 4 * c];
                pa[nd][0] = v.x; pa[nd][1] = v.y; pa[nd][2] = v.z; pa[nd][3] = v.w;
            }
#pragma unroll
            for (int fi = 0; fi < 4; fi++) {
                float wl = LW[(fb + 4 * c + fi) * 64 + l];
#pragma unroll
                for (int nd = 0; nd < 4; nd++) lw[nd] = fmaf(pa[nd][fi], wl, lw[nd]);
            }
        }
#pragma unroll
        for (int nd = 0; nd < 4; nd++) qp[w][nd][l] = lw[nd];
    }
    __syncthreads();

    // ---- own-node LayerNorm + ReLU + residual ----
    {
        float a = wsf[OFF_LB + l] + qp[0][w][l] + qp[1][w][l] + qp[2][w][l] + qp[3][w][l];
        float s1 = a, sq = a * a;
#pragma unroll
        for (int o = 1; o < 64; o <<= 1) { s1 += __shfl_xor(s1, o); sq += __shfl_xor(sq, o); }
        float mu = s1 * (1.0f / 64.0f);
        float varl = sq * (1.0f / 64.0f) - mu * mu;
        float ln = (a - mu) * rsqrtf(varl + 1e-5f) * wsf[OFF_LG + l] + wsf[OFF_LBN + l];
        if (active) {
            long idx = (long)n * 64 + l;
            float res = xrow[w][l] + fmaxf(ln, 0.f);
            if (mode == 0) ((u16*)outp)[idx] = f2bf(res);
            else           ((float*)outp)[idx] = res;
        }
    }
}

extern "C" void kernel_launch(void* const* d_in, const int* in_sizes, int n_in,
                              void* d_out, int out_size, void* d_ws, size_t ws_size,
                              hipStream_t stream) {
    const void* atom_x   = d_in[0];
    const void* bond_emb = d_in[1];
    const void* edge_w   = d_in[2];
    const void* edge_b   = d_in[3];
    const void* pre_w1   = d_in[4];
    const void* pre_b1   = d_in[5];
    const void* pre_w2   = d_in[6];
    const void* pre_b2   = d_in[7];
    const void* post_w1  = d_in[8];
    const void* post_b1  = d_in[9];
    const void* post_w2  = d_in[10];
    const void* post_b2  = d_in[11];
    const void* lin_w    = d_in[12];
    const void* lin_b    = d_in[13];
    const void* ln_g     = d_in[14];
    const void* ln_b     = d_in[15];
    const int* bond_x    = (const int*)d_in[16];
    const int* aei       = (const int*)d_in[17];

    int E  = in_sizes[16];
    int Nn = in_sizes[0] / 64;
    const int* srcp = aei;
    const int* dstp = aei + E;

    float* wsf = (float*)d_ws;
    int*   wsi = (int*)d_ws;

    size_t o = IB;
    int* modep = wsi + o; o += 16;
    int* cnt   = wsi + o; o += Nn;
    o = (o + 63) & ~(size_t)63;
    int* pk    = wsi + o; o += (size_t)Nn * MAXD;
    float* Yp  = (float*)(wsi + o); o += (size_t)Nn * 64;
    float* XWp = (float*)(wsi + o); o += (size_t)Nn * 64;
    // ws usage ~39 MB

    const int NIB  = 1600;
    const int SBLK = (E + 255) / 256;

    (void)hipMemsetAsync(cnt, 0, (size_t)Nn * sizeof(int), stream);
    k_prep<<<NIB + SBLK, 256, 0, stream>>>(dstp, srcp, bond_x,
                                           bond_emb, edge_w, edge_b,
                                           pre_w1, pre_b1, pre_w2, pre_b2,
                                           post_w1, post_b1, post_w2, post_b2,
                                           lin_w, lin_b, ln_g, ln_b,
                                           atom_x, wsf, Yp, XWp, cnt, pk, modep, Nn, E, NIB);
    dim3 gn((Nn + 3) / 4, 1, 1);
    k_node<<<gn, 256, 0, stream>>>(atom_x, Yp, XWp, pk, cnt, wsf, d_out, modep, Nn);
}